// Round 3
// baseline (296.295 us; speedup 1.0000x reference)
//
#include <hip/hip_runtime.h>
#include <hip/hip_bf16.h>
#include <math.h>

#define B 4
#define A 256
#define NN 64
#define NCB 128
#define NF 128
#define NSB 50
#define BA (B*A)
#define PAIRS (BA*NN)

typedef __bf16 bf;
typedef __attribute__((ext_vector_type(8))) __bf16 bfrag8;
typedef __attribute__((ext_vector_type(4))) float ffrag4;

// ---- module-scope scratch (never touches inputs / d_ws) ----
__device__ __attribute__((aligned(16))) bf    g_yib[BA*NF];             // bf16(xi @ in2f_W)
__device__ __attribute__((aligned(16))) bf    g_vij[(size_t)PAIRS*NCB]; // bf16 vij stash (16 MB)
__device__ __attribute__((aligned(16))) float g_vik[BA*NCB*3];          // fp32 Vik rows [ba][c*3+d]
// transposed bf16 weights, layout [n][k] (k contiguous). tf1 padded to K=64.
__device__ __attribute__((aligned(16))) bf g_tf1[NF*64];
__device__ __attribute__((aligned(16))) bf g_tf2[NF*NF];
__device__ __attribute__((aligned(16))) bf g_tfo[NF*NF];
__device__ __attribute__((aligned(16))) bf g_tp1[NF*NF];
__device__ __attribute__((aligned(16))) bf g_tp2[NF*NF];
__device__ __attribute__((aligned(16))) bf g_te1[NF*NF];
__device__ __attribute__((aligned(16))) bf g_te2[NF*NF];

// fast ssp: softplus(x)-ln2 via hw v_exp_f32/v_log_f32
__device__ __forceinline__ float ssp(float x){
    float e = __expf(-fabsf(x));
    return fmaxf(x, 0.f) + __logf(1.f + e) - 0.6931471805599453f;
}

// ---- weight pre-transpose: W[k][n] fp32 -> Wt[n][k] bf16 (tf1 K-pad to 64) ----
__global__ __launch_bounds__(256)
void k_wt(const float* __restrict__ f1, const float* __restrict__ f2,
          const float* __restrict__ fo, const float* __restrict__ p1,
          const float* __restrict__ p2, const float* __restrict__ e1,
          const float* __restrict__ e2){
    int s = blockIdx.x >> 3, part = blockIdx.x & 7;
    const float* src; bf* dst; int kb, realK;
    if (s == 0){ src = f1; dst = g_tf1; kb = 6; realK = NSB; }
    else {
        kb = 7; realK = 128;
        src = (s==1)?f2:(s==2)?fo:(s==3)?p1:(s==4)?p2:(s==5)?e1:e2;
        dst = (s==1)?g_tf2:(s==2)?g_tfo:(s==3)?g_tp1:(s==4)?g_tp2:(s==5)?g_te1:g_te2;
    }
    int total = NF << kb;
    int chunk = total >> 3;
    int end = (part + 1) * chunk;
    for (int e = part*chunk + threadIdx.x; e < end; e += 256){
        int n = e >> kb, k = e & ((1<<kb)-1);
        dst[e] = (k < realK) ? (bf)src[k*NF + n] : (bf)0.f;
    }
}

// ---- g_yib[row][f] = bf16( xi[row,:] @ in2f_W[:,f] ) ----
__global__ __launch_bounds__(NF)
void k_yi(const float* __restrict__ xi, const float* __restrict__ W){
    int row = blockIdx.x, f = threadIdx.x;
    __shared__ float x[NCB];
    x[f] = xi[row*NCB + f];
    __syncthreads();
    float s = 0.f;
    #pragma unroll 16
    for (int c = 0; c < NCB; c++) s += x[c]*W[c*NF + f];
    g_yib[row*NF + f] = (bf)s;
}

// ---- per-wave GEMM stage: B-frags read DIRECTLY from global (L1/L2-resident
// weights) in the exact layout previously read from sW. No LDS staging, no
// barriers. Epilogue is a per-nt functor so the live register set stays tiny.
template<int NKT, class EPI>
__device__ __forceinline__ void stageG(const bf* __restrict__ gW,
                                       const bfrag8* afr, int c16, int q, EPI epi){
    #pragma unroll
    for (int nt = 0; nt < 8; nt++){
        ffrag4 a = {0.f,0.f,0.f,0.f};
        #pragma unroll
        for (int kt = 0; kt < NKT; kt++){
            bfrag8 bv = *(const bfrag8*)&gW[(nt*16 + c16)*(NKT*32) + kt*32 + q*8];
            a = __builtin_amdgcn_mfma_f32_16x16x32_bf16(afr[kt], bv, a, 0, 0, 0);
        }
        epi(nt, a);
    }
}

#define RDA4(SRC) { _Pragma("unroll") for (int kt = 0; kt < 4; kt++) \
    afr[kt] = *(const bfrag8*)&SRC[arow*136 + kt*32 + q*8]; }

__global__ __launch_bounds__(256, 4)
void k_main(const float* __restrict__ r_ij, const float* __restrict__ cos_ij,
            const float* __restrict__ f_ij, const float* __restrict__ mask,
            const int* __restrict__ neighbors,
            const float* __restrict__ fb1, const float* __restrict__ fb2,
            const float* __restrict__ f2b,
            const float* __restrict__ aW1, const float* __restrict__ ab1,
            const float* __restrict__ aW2, const float* __restrict__ ab2,
            const float* __restrict__ pb1, const float* __restrict__ pb2,
            const float* __restrict__ eb1, const float* __restrict__ eb2,
            float* __restrict__ out_vi){
    const int tid  = threadIdx.x;
    const int ba   = blockIdx.x;          // atom (b*A + a)
    const int b    = ba >> 8;
    const int w    = tid >> 6;            // wave 0..3 -> rows w*16..w*16+15
    const int lane = tid & 63;
    const int q    = lane >> 4;
    const int c16  = lane & 15;
    const int arow = w*16 + c16;          // A-frag row for this lane

    // Everything below is WAVE-PRIVATE (each wave owns its 16 rows of sA/sA2)
    // until the finale. Zero __syncthreads in the GEMM chain.
    __shared__ __attribute__((aligned(16))) bf sA [64*136];   // h1/u/v  (+finale scratch)
    __shared__ __attribute__((aligned(16))) bf sA2[64*136];   // f / hp / vij / he
    __shared__ float sCosM[64*4];   // cos0,cos1,cos2,mask
    __shared__ float sCr[64];
    __shared__ int   sJb[64];       // (b*A+j)*NF

    // ---- wave-local preload: f_ij rows -> sA2 (K zero-padded to 64) ----
    #pragma unroll
    for (int i = 0; i < 16; i++){
        int row = w*16 + i;
        float v = (lane < NSB) ? f_ij[(ba*64 + row)*NSB + lane] : 0.f;
        sA2[row*136 + lane] = (bf)v;
    }
    if (lane < 16){
        int row = w*16 + lane;
        int p = ba*64 + row;
        sCosM[row*4+0] = cos_ij[p*3+0];
        sCosM[row*4+1] = cos_ij[p*3+1];
        sCosM[row*4+2] = cos_ij[p*3+2];
        sCosM[row*4+3] = mask[p];
        float r = r_ij[p];
        sCr[row] = (r < 5.f) ? 0.5f*(__cosf(r*0.62831853071795864769f) + 1.f) : 0.f;
        int j = neighbors[p] & (A-1);
        sJb[row] = (b*A + j)*NF;
    }
    // no barrier: in-order LDS ops within the wave; lanes run in lockstep.

    bfrag8 afr[4];

    // ===== S1: h1 = ssp(f @ fW1 + fb1) -> sA  (K=64) =====
    #pragma unroll
    for (int kt = 0; kt < 2; kt++) afr[kt] = *(const bfrag8*)&sA2[arow*136 + kt*32 + q*8];
    stageG<2>(g_tf1, afr, c16, q, [&](int nt, ffrag4 a){
        int col = nt*16 + c16;
        float bias = fb1[col];
        #pragma unroll
        for (int rg = 0; rg < 4; rg++){
            int row = w*16 + q*4 + rg;
            sA[row*136 + col] = (bf)ssp(a[rg] + bias);
        }
    });

    // ===== S2: Wf = (h1 @ fW2 + fb2)*C ; u = yj*Wf -> sA (in-place) =====
    RDA4(sA);
    stageG<4>(g_tf2, afr, c16, q, [&](int nt, ffrag4 a){
        int col = nt*16 + c16;
        float bias = fb2[col];
        #pragma unroll
        for (int rg = 0; rg < 4; rg++){
            int row = w*16 + q*4 + rg;
            float wf = (a[rg] + bias) * sCr[row];
            sA[row*136 + col] = (bf)((float)g_yib[sJb[row] + col] * wf);
        }
    });

    // ===== S3: v = ssp(u @ f2W + f2b) -> sA (in-place); vsum partials =====
    float vsAll[8];
    #pragma unroll
    for (int t = 0; t < 8; t++) vsAll[t] = 0.f;
    RDA4(sA);
    stageG<4>(g_tfo, afr, c16, q, [&](int nt, ffrag4 a){
        int col = nt*16 + c16;
        float bias = f2b[col];
        #pragma unroll
        for (int rg = 0; rg < 4; rg++){
            int row = w*16 + q*4 + rg;
            float v = ssp(a[rg] + bias);
            sA[row*136 + col] = (bf)v;
            vsAll[nt] += v * sCosM[row*4+3];
        }
    });

    // ===== S4: hp = ssp(v @ pW1 + pb1) -> sA2 =====
    RDA4(sA);
    stageG<4>(g_tp1, afr, c16, q, [&](int nt, ffrag4 a){
        int col = nt*16 + c16;
        float bias = pb1[col];
        #pragma unroll
        for (int rg = 0; rg < 4; rg++){
            int row = w*16 + q*4 + rg;
            sA2[row*136 + col] = (bf)ssp(a[rg] + bias);
        }
    });

    // ===== S5: vij = hp @ pW2 + pb2 -> sA2 (in-place, bf16) =====
    RDA4(sA2);
    stageG<4>(g_tp2, afr, c16, q, [&](int nt, ffrag4 a){
        int col = nt*16 + c16;
        float bias = pb2[col];
        #pragma unroll
        for (int rg = 0; rg < 4; rg++){
            int row = w*16 + q*4 + rg;
            sA2[row*136 + col] = (bf)(a[rg] + bias);
        }
    });

    // ===== S6: stream wave's vij rows -> g_vij; he = ssp(v @ eW1 + eb1) -> sA2 =====
    #pragma unroll
    for (int i = 0; i < 4; i++){
        int row = w*16 + i*4 + (lane >> 4);
        int cp  = c16*8;
        *(bfrag8*)&g_vij[((size_t)ba*64 + row)*128 + cp] = *(const bfrag8*)&sA2[row*136 + cp];
    }
    RDA4(sA);                                  // v still lives in sA
    stageG<4>(g_te1, afr, c16, q, [&](int nt, ffrag4 a){
        int col = nt*16 + c16;
        float bias = eb1[col];
        #pragma unroll
        for (int rg = 0; rg < 4; rg++){
            int row = w*16 + q*4 + rg;
            sA2[row*136 + col] = (bf)ssp(a[rg] + bias);
        }
    });

    // ===== S7: vik = he @ eW2 + eb2 ; Vik partials (registers only) =====
    float vkAll[8][3];
    #pragma unroll
    for (int t = 0; t < 8; t++){ vkAll[t][0]=0.f; vkAll[t][1]=0.f; vkAll[t][2]=0.f; }
    RDA4(sA2);
    stageG<4>(g_te2, afr, c16, q, [&](int nt, ffrag4 a){
        float bias = eb2[nt*16 + c16];
        #pragma unroll
        for (int rg = 0; rg < 4; rg++){
            int row = w*16 + q*4 + rg;
            float vik = (a[rg] + bias) * sCosM[row*4+3];
            vkAll[nt][0] += vik * sCosM[row*4+0];
            vkAll[nt][1] += vik * sCosM[row*4+1];
            vkAll[nt][2] += vik * sCosM[row*4+2];
        }
    });

    // ===== finale: the ONLY barrier — cross-wave reduction, reuse sA =====
    __syncthreads();
    float* const sVs   = (float*)sA;                   // 4*128 floats
    float* const sVk   = (float*)((char*)sA + 2048);   // 4*384 floats
    float* const sVsum = (float*)((char*)sA + 8192);   // 128 floats
    float* const sHa   = (float*)((char*)sA + 8704);   // 128 floats
    #pragma unroll
    for (int t = 0; t < 8; t++){
        float v = vsAll[t];
        v += __shfl_xor(v, 16);
        v += __shfl_xor(v, 32);
        if (q == 0) sVs[w*128 + t*16 + c16] = v;
    }
    #pragma unroll
    for (int t = 0; t < 8; t++){
        #pragma unroll
        for (int d = 0; d < 3; d++){
            float v = vkAll[t][d];
            v += __shfl_xor(v, 16);
            v += __shfl_xor(v, 32);
            if (q == 0) sVk[w*384 + (t*16 + c16)*3 + d] = v;
        }
    }
    __syncthreads();

    for (int e = tid; e < 384; e += 256)
        g_vik[ba*384 + e] = sVk[e] + sVk[384+e] + sVk[768+e] + sVk[1152+e];
    if (tid < 128)
        sVsum[tid] = sVs[tid] + sVs[128+tid] + sVs[256+tid] + sVs[384+tid];
    __syncthreads();
    if (tid < 128){
        float acc2 = ab1[tid];
        #pragma unroll 16
        for (int k = 0; k < 128; k++) acc2 += sVsum[k]*aW1[k*128 + tid];
        sHa[tid] = ssp(acc2);
    }
    __syncthreads();
    if (tid < 128){
        float acc2 = ab2[tid];
        #pragma unroll 16
        for (int k = 0; k < 128; k++) acc2 += sHa[k]*aW2[k*128 + tid];
        out_vi[ba*128 + tid] = acc2;
    }
}

// ---- V[p,c,d] = vij[p,c]*cos[p,d] + Vik[ba] + Vik[j] ----
// Block-per-atom; stage vij/Vik_a/cos/J once, then write the atom's 24,576
// output floats LINEARLY: every store instruction is a dense 256 B/wave run,
// nontemporal (write-once 96 MB, keep it out of L2). Vjl gather is contiguous
// per-pair from L2-resident g_vik.
__global__ __launch_bounds__(256)
void k_V(const float* __restrict__ cos_ij, const int* __restrict__ nbrs,
         float* __restrict__ outV){
    const int ba  = blockIdx.x;
    const int b   = ba >> 8;
    const int tid = threadIdx.x;
    __shared__ __attribute__((aligned(16))) bf sVij[64*128];   // 16 KB
    __shared__ float sVa[384];
    __shared__ float sC[64*4];
    __shared__ int   sJ[64];
    #pragma unroll
    for (int i = 0; i < 4; i++){
        int e8 = tid + i*256;                  // 1024 x bfrag8
        *(bfrag8*)&sVij[e8*8] = *(const bfrag8*)&g_vij[(size_t)ba*8192 + e8*8];
    }
    for (int e = tid; e < 384; e += 256) sVa[e] = g_vik[ba*384 + e];
    if (tid < 64){
        int p = ba*64 + tid;
        sJ[tid] = (b*A + (nbrs[p] & (A-1)))*384;
        sC[tid*4+0] = cos_ij[p*3+0];
        sC[tid*4+1] = cos_ij[p*3+1];
        sC[tid*4+2] = cos_ij[p*3+2];
    }
    __syncthreads();
    float* const oBase = outV + (size_t)ba*24576;
    #pragma unroll 4
    for (int it = 0; it < 96; it++){
        int E  = it*256 + tid;                 // 0..24575 linear in output
        int pl = E / 384;                      // pair-local
        int e  = E - pl*384;                   // c*3+d
        int c  = e / 3;
        int d  = e - c*3;
        float vv  = (float)sVij[pl*128 + c];
        float val = fmaf(vv, sC[pl*4+d], sVa[e] + g_vik[sJ[pl] + e]);
        __builtin_nontemporal_store(val, oBase + E);
    }
}

extern "C" void kernel_launch(void* const* d_in, const int* in_sizes, int n_in,
                              void* d_out, int out_size, void* d_ws, size_t ws_size,
                              hipStream_t stream){
    const float* xi      = (const float*)d_in[0];
    const float* r_ij    = (const float*)d_in[1];
    const float* cos_ij  = (const float*)d_in[2];
    const float* f_ij    = (const float*)d_in[3];
    const float* nmask   = (const float*)d_in[4];
    const float* fW1     = (const float*)d_in[5];
    const float* fb1     = (const float*)d_in[6];
    const float* fW2     = (const float*)d_in[7];
    const float* fb2     = (const float*)d_in[8];
    const float* in2f_W  = (const float*)d_in[9];
    const float* f2W     = (const float*)d_in[10];
    const float* f2b     = (const float*)d_in[11];
    const float* aW1     = (const float*)d_in[12];
    const float* ab1     = (const float*)d_in[13];
    const float* aW2     = (const float*)d_in[14];
    const float* ab2     = (const float*)d_in[15];
    const float* pW1     = (const float*)d_in[16];
    const float* pb1     = (const float*)d_in[17];
    const float* pW2     = (const float*)d_in[18];
    const float* pb2     = (const float*)d_in[19];
    const float* eW1     = (const float*)d_in[20];
    const float* eb1     = (const float*)d_in[21];
    const float* eW2     = (const float*)d_in[22];
    const float* eb2     = (const float*)d_in[23];
    const int*  nbrs     = (const int*)d_in[24];

    float* out_vi = (float*)d_out;             // [B,A,NCB] fp32
    float* outV   = (float*)d_out + BA*NCB;    // [B,A,N,NCB,3] fp32

    k_wt<<<56, 256, 0, stream>>>(fW1, fW2, f2W, pW1, pW2, eW1, eW2);
    k_yi<<<BA, NF, 0, stream>>>(xi, in2f_W);

    k_main<<<BA, 256, 0, stream>>>(r_ij, cos_ij, f_ij, nmask, nbrs,
                                   fb1, fb2, f2b,
                                   aW1, ab1, aW2, ab2,
                                   pb1, pb2, eb1, eb2,
                                   out_vi);

    k_V<<<BA, 256, 0, stream>>>(cos_ij, nbrs, outV);
}

// Round 5
// 235.843 us; speedup vs baseline: 1.2563x; 1.2563x over previous
//
#include <hip/hip_runtime.h>
#include <hip/hip_bf16.h>
#include <math.h>

#define B 4
#define A 256
#define NN 64
#define NCB 128
#define NF 128
#define NSB 50
#define BA (B*A)
#define PAIRS (BA*NN)

typedef __bf16 bf;
typedef __attribute__((ext_vector_type(8))) __bf16 bfrag8;
typedef __attribute__((ext_vector_type(4))) float ffrag4;

// ---- module-scope scratch (never touches inputs / d_ws) ----
__device__ __attribute__((aligned(16))) bf    g_yib[BA*NF];             // bf16(xi @ in2f_W)
__device__ __attribute__((aligned(16))) bf    g_vij[(size_t)PAIRS*NCB]; // bf16 vij stash (16 MB)
__device__ __attribute__((aligned(16))) float g_vik[BA*NCB*3];          // fp32 Vik rows [ba][c*3+d]
// transposed bf16 weights, layout [n][k] (k contiguous). tf1 padded to K=64.
__device__ __attribute__((aligned(16))) bf g_tf1[NF*64];
__device__ __attribute__((aligned(16))) bf g_tf2[NF*NF];
__device__ __attribute__((aligned(16))) bf g_tfo[NF*NF];
__device__ __attribute__((aligned(16))) bf g_tp1[NF*NF];
__device__ __attribute__((aligned(16))) bf g_tp2[NF*NF];
__device__ __attribute__((aligned(16))) bf g_te1[NF*NF];
__device__ __attribute__((aligned(16))) bf g_te2[NF*NF];

// fast ssp: softplus(x)-ln2 via hw v_exp_f32/v_log_f32
__device__ __forceinline__ float ssp(float x){
    float e = __expf(-fabsf(x));
    return fmaxf(x, 0.f) + __logf(1.f + e) - 0.6931471805599453f;
}

// ---- weight pre-transpose: W[k][n] fp32 -> Wt[n][k] bf16 (tf1 K-pad to 64) ----
__global__ __launch_bounds__(256)
void k_wt(const float* __restrict__ f1, const float* __restrict__ f2,
          const float* __restrict__ fo, const float* __restrict__ p1,
          const float* __restrict__ p2, const float* __restrict__ e1,
          const float* __restrict__ e2){
    int s = blockIdx.x >> 3, part = blockIdx.x & 7;
    const float* src; bf* dst; int kb, realK;
    if (s == 0){ src = f1; dst = g_tf1; kb = 6; realK = NSB; }
    else {
        kb = 7; realK = 128;
        src = (s==1)?f2:(s==2)?fo:(s==3)?p1:(s==4)?p2:(s==5)?e1:e2;
        dst = (s==1)?g_tf2:(s==2)?g_tfo:(s==3)?g_tp1:(s==4)?g_tp2:(s==5)?g_te1:g_te2;
    }
    int total = NF << kb;
    int chunk = total >> 3;
    int end = (part + 1) * chunk;
    for (int e = part*chunk + threadIdx.x; e < end; e += 256){
        int n = e >> kb, k = e & ((1<<kb)-1);
        dst[e] = (k < realK) ? (bf)src[k*NF + n] : (bf)0.f;
    }
}

// ---- g_yib[row][f] = bf16( xi[row,:] @ in2f_W[:,f] ) ----
__global__ __launch_bounds__(NF)
void k_yi(const float* __restrict__ xi, const float* __restrict__ W){
    int row = blockIdx.x, f = threadIdx.x;
    __shared__ float x[NCB];
    x[f] = xi[row*NCB + f];
    __syncthreads();
    float s = 0.f;
    #pragma unroll 16
    for (int c = 0; c < NCB; c++) s += x[c]*W[c*NF + f];
    g_yib[row*NF + f] = (bf)s;
}

// ---- LDS staging helpers (block-cooperative, coalesced) ----
__device__ __forceinline__ void stage_w128(bf* __restrict__ sW, const bf* __restrict__ g,
                                           int half, int tid){
    #pragma unroll
    for (int i = 0; i < 4; i++){
        int r  = i*16 + (tid >> 4);
        int cp = (tid & 15)*8;
        *(bfrag8*)&sW[r*136 + cp] = *(const bfrag8*)&g[(half*64 + r)*128 + cp];
    }
}
__device__ __forceinline__ void stage_w64(bf* __restrict__ sW, const bf* __restrict__ g,
                                          int half, int tid){
    #pragma unroll
    for (int i = 0; i < 2; i++){
        int r  = i*32 + (tid >> 3);
        int cp = (tid & 7)*8;
        *(bfrag8*)&sW[r*72 + cp] = *(const bfrag8*)&g[(half*64 + r)*64 + cp];
    }
}
__device__ __forceinline__ void gemm4(const bf* __restrict__ sW, const bfrag8 afr[4],
                                      ffrag4 acc[4], int q, int c16){
    #pragma unroll
    for (int nt = 0; nt < 4; nt++){
        ffrag4 a = {0.f,0.f,0.f,0.f};
        #pragma unroll
        for (int kt = 0; kt < 4; kt++){
            bfrag8 bv = *(const bfrag8*)&sW[(nt*16 + c16)*136 + kt*32 + q*8];
            a = __builtin_amdgcn_mfma_f32_16x16x32_bf16(afr[kt], bv, a, 0, 0, 0);
        }
        acc[nt] = a;
    }
}
__device__ __forceinline__ void gemm2(const bf* __restrict__ sW, const bfrag8 afr[2],
                                      ffrag4 acc[4], int q, int c16){
    #pragma unroll
    for (int nt = 0; nt < 4; nt++){
        ffrag4 a = {0.f,0.f,0.f,0.f};
        #pragma unroll
        for (int kt = 0; kt < 2; kt++){
            bfrag8 bv = *(const bfrag8*)&sW[(nt*16 + c16)*72 + kt*32 + q*8];
            a = __builtin_amdgcn_mfma_f32_16x16x32_bf16(afr[kt], bv, a, 0, 0, 0);
        }
        acc[nt] = a;
    }
}

#define RDA4(DST) { _Pragma("unroll") for (int kt = 0; kt < 4; kt++) \
    DST[kt] = *(const bfrag8*)&sX[arow*136 + kt*32 + q*8]; }

// epilogue macros (H = half of current stage), all writes wave-private rows
#define EPI_SSP(BIASP, H) \
    { _Pragma("unroll") for (int nt = 0; nt < 4; nt++){ \
        int col = ((H)*4 + nt)*16 + c16; \
        float bias = BIASP[col]; \
        _Pragma("unroll") for (int rg = 0; rg < 4; rg++){ \
            int row = w*16 + q*4 + rg; \
            sX[row*136 + col] = (bf)ssp(acc[nt][rg] + bias); \
        } } }

#define EPI_LIN(BIASP, H) \
    { _Pragma("unroll") for (int nt = 0; nt < 4; nt++){ \
        int col = ((H)*4 + nt)*16 + c16; \
        float bias = BIASP[col]; \
        _Pragma("unroll") for (int rg = 0; rg < 4; rg++){ \
            int row = w*16 + q*4 + rg; \
            sX[row*136 + col] = (bf)(acc[nt][rg] + bias); \
        } } }

__global__ __launch_bounds__(256, 4)
void k_main(const float* __restrict__ r_ij, const float* __restrict__ cos_ij,
            const float* __restrict__ f_ij, const float* __restrict__ mask,
            const int* __restrict__ neighbors,
            const float* __restrict__ fb1, const float* __restrict__ fb2,
            const float* __restrict__ f2b,
            const float* __restrict__ aW1, const float* __restrict__ ab1,
            const float* __restrict__ aW2, const float* __restrict__ ab2,
            const float* __restrict__ pb1, const float* __restrict__ pb2,
            const float* __restrict__ eb1, const float* __restrict__ eb2,
            float* __restrict__ out_vi){
    const int tid  = threadIdx.x;
    const int ba   = blockIdx.x;          // atom (b*A + a)
    const int b    = ba >> 8;
    const int w    = tid >> 6;            // wave 0..3 -> rows w*16..w*16+15
    const int lane = tid & 63;
    const int q    = lane >> 4;
    const int c16  = lane & 15;
    const int arow = w*16 + c16;          // A-frag row for this lane

    // LDS budget 36,352 B -> 4 blocks/CU (the r1->r3 lesson: concurrency,
    // not barrier elimination, is what hides the rendezvous).
    __shared__ __attribute__((aligned(16))) bf sW[64*136];   // staged weights (shared)
    __shared__ __attribute__((aligned(16))) bf sX[64*136];   // SINGLE activation buf (wave-private rows)
    __shared__ float sCosM[64*4];
    __shared__ float sCr[64];
    __shared__ int   sJb[64];

    // ---- wave-private preload: f_ij rows -> sX (K zero-padded to 64) ----
    #pragma unroll
    for (int i = 0; i < 16; i++){
        int row = w*16 + i;
        float v = (lane < NSB) ? f_ij[(ba*64 + row)*NSB + lane] : 0.f;
        sX[row*136 + lane] = (bf)v;
    }
    if (lane < 16){
        int row = w*16 + lane;
        int p = ba*64 + row;
        sCosM[row*4+0] = cos_ij[p*3+0];
        sCosM[row*4+1] = cos_ij[p*3+1];
        sCosM[row*4+2] = cos_ij[p*3+2];
        sCosM[row*4+3] = mask[p];
        float r = r_ij[p];
        sCr[row] = (r < 5.f) ? 0.5f*(__cosf(r*0.62831853071795864769f) + 1.f) : 0.f;
        int j = neighbors[p] & (A-1);
        sJb[row] = (b*A + j)*NF;
    }
    // no barrier needed: sX/sCosM/sCr/sJb rows are wave-private (r3-verified)

    bfrag8 afr[4], afrV[4], afr2[2]; ffrag4 acc[4];

    // ===== S1: h1 = ssp(f @ fW1 + fb1) -> sX  (K=64) =====
    #pragma unroll
    for (int kt = 0; kt < 2; kt++) afr2[kt] = *(const bfrag8*)&sX[arow*136 + kt*32 + q*8];
    #pragma unroll
    for (int half = 0; half < 2; half++){
        if (half) __syncthreads();
        stage_w64(sW, g_tf1, half, tid);
        __syncthreads();
        gemm2(sW, afr2, acc, q, c16);
        EPI_SSP(fb1, half);
    }
    RDA4(afr);                               // A-frags: h1
    __syncthreads();

    // ===== S2: Wf = (h1 @ fW2 + fb2)*C ; u = yj*Wf -> sX =====
    #pragma unroll
    for (int half = 0; half < 2; half++){
        if (half) __syncthreads();
        stage_w128(sW, g_tf2, half, tid);
        __syncthreads();
        gemm4(sW, afr, acc, q, c16);
        #pragma unroll
        for (int nt = 0; nt < 4; nt++){
            int col = (half*4 + nt)*16 + c16;
            float bias = fb2[col];
            #pragma unroll
            for (int rg = 0; rg < 4; rg++){
                int row = w*16 + q*4 + rg;
                float wf = (acc[nt][rg] + bias) * sCr[row];
                sX[row*136 + col] = (bf)((float)g_yib[sJb[row] + col] * wf);
            }
        }
    }
    RDA4(afr);                               // A-frags: u
    __syncthreads();

    // ===== S3: v = ssp(u @ f2W + f2b) -> sX ; vsum partials =====
    float vsAll[8];
    #pragma unroll
    for (int t = 0; t < 8; t++) vsAll[t] = 0.f;
    #pragma unroll
    for (int half = 0; half < 2; half++){
        if (half) __syncthreads();
        stage_w128(sW, g_tfo, half, tid);
        __syncthreads();
        gemm4(sW, afr, acc, q, c16);
        #pragma unroll
        for (int nt = 0; nt < 4; nt++){
            int col = (half*4 + nt)*16 + c16;
            float bias = f2b[col];
            #pragma unroll
            for (int rg = 0; rg < 4; rg++){
                int row = w*16 + q*4 + rg;
                float v = ssp(acc[nt][rg] + bias);
                sX[row*136 + col] = (bf)v;
                vsAll[half*4 + nt] += v * sCosM[row*4+3];
            }
        }
    }
    RDA4(afrV);                              // A-frags: v — HELD IN REGS for S4 AND S6
    __syncthreads();

    // ===== S4: hp = ssp(v @ pW1 + pb1) -> sX =====
    #pragma unroll
    for (int half = 0; half < 2; half++){
        if (half) __syncthreads();
        stage_w128(sW, g_tp1, half, tid);
        __syncthreads();
        gemm4(sW, afrV, acc, q, c16);
        EPI_SSP(pb1, half);
    }
    RDA4(afr);                               // A-frags: hp
    __syncthreads();

    // ===== S5: vij = hp @ pW2 + pb2 -> sX (linear) =====
    #pragma unroll
    for (int half = 0; half < 2; half++){
        if (half) __syncthreads();
        stage_w128(sW, g_tp2, half, tid);
        __syncthreads();
        gemm4(sW, afr, acc, q, c16);
        EPI_LIN(pb2, half);
    }
    // stream wave's vij rows -> g_vij (wave-ordered before he overwrites sX)
    #pragma unroll
    for (int i = 0; i < 4; i++){
        int row = w*16 + i*4 + (lane >> 4);
        int cp  = c16*8;
        *(bfrag8*)&g_vij[((size_t)ba*64 + row)*128 + cp] = *(const bfrag8*)&sX[row*136 + cp];
    }
    __syncthreads();

    // ===== S6: he = ssp(v @ eW1 + eb1) -> sX  (input = afrV, still live) =====
    #pragma unroll
    for (int half = 0; half < 2; half++){
        if (half) __syncthreads();
        stage_w128(sW, g_te1, half, tid);
        __syncthreads();
        gemm4(sW, afrV, acc, q, c16);
        EPI_SSP(eb1, half);
    }
    RDA4(afr);                               // A-frags: he
    __syncthreads();

    // ===== S7: vik = he @ eW2 + eb2 ; Vik partials (registers only) =====
    float vkAll[8][3];
    #pragma unroll
    for (int t = 0; t < 8; t++){ vkAll[t][0]=0.f; vkAll[t][1]=0.f; vkAll[t][2]=0.f; }
    #pragma unroll
    for (int half = 0; half < 2; half++){
        if (half) __syncthreads();
        stage_w128(sW, g_te2, half, tid);
        __syncthreads();
        gemm4(sW, afr, acc, q, c16);
        #pragma unroll
        for (int nt = 0; nt < 4; nt++){
            float bias = eb2[(half*4 + nt)*16 + c16];
            #pragma unroll
            for (int rg = 0; rg < 4; rg++){
                int row = w*16 + q*4 + rg;
                float vik = (acc[nt][rg] + bias) * sCosM[row*4+3];
                vkAll[half*4 + nt][0] += vik * sCosM[row*4+0];
                vkAll[half*4 + nt][1] += vik * sCosM[row*4+1];
                vkAll[half*4 + nt][2] += vik * sCosM[row*4+2];
            }
        }
    }

    // ===== finale: cross-wave reduction, reuse sX as scratch =====
    __syncthreads();
    float* const sVs   = (float*)sX;                   // 4*128 floats
    float* const sVk   = (float*)((char*)sX + 2048);   // 4*384 floats
    float* const sVsum = (float*)((char*)sX + 8192);   // 128 floats
    float* const sHa   = (float*)((char*)sX + 8704);   // 128 floats
    #pragma unroll
    for (int t = 0; t < 8; t++){
        float v = vsAll[t];
        v += __shfl_xor(v, 16);
        v += __shfl_xor(v, 32);
        if (q == 0) sVs[w*128 + t*16 + c16] = v;
    }
    #pragma unroll
    for (int t = 0; t < 8; t++){
        #pragma unroll
        for (int d = 0; d < 3; d++){
            float v = vkAll[t][d];
            v += __shfl_xor(v, 16);
            v += __shfl_xor(v, 32);
            if (q == 0) sVk[w*384 + (t*16 + c16)*3 + d] = v;
        }
    }
    __syncthreads();

    for (int e = tid; e < 384; e += 256)
        g_vik[ba*384 + e] = sVk[e] + sVk[384+e] + sVk[768+e] + sVk[1152+e];
    if (tid < 128)
        sVsum[tid] = sVs[tid] + sVs[128+tid] + sVs[256+tid] + sVs[384+tid];
    __syncthreads();
    if (tid < 128){
        float acc2 = ab1[tid];
        #pragma unroll 16
        for (int k = 0; k < 128; k++) acc2 += sVsum[k]*aW1[k*128 + tid];
        sHa[tid] = ssp(acc2);
    }
    __syncthreads();
    if (tid < 128){
        float acc2 = ab2[tid];
        #pragma unroll 16
        for (int k = 0; k < 128; k++) acc2 += sHa[k]*aW2[k*128 + tid];
        out_vi[ba*128 + tid] = acc2;
    }
}

// ---- V[p,c,d] = vij[p,c]*cos[p,d] + Vik[ba] + Vik[j] ----
// Block-per-atom; stage vij/Vik_a/cos/J once; write the atom's 24,576 output
// floats LINEARLY as 16B nontemporal stores (dense 1 KB/wave/instr).
// A 4-float group never crosses a pair boundary (384 % 4 == 0).
// NOTE: __builtin_nontemporal_store needs a clang vector type (ffrag4),
// not HIP's float4 struct (r4 compile failure).
__global__ __launch_bounds__(256)
void k_V(const float* __restrict__ cos_ij, const int* __restrict__ nbrs,
         float* __restrict__ outV){
    const int ba  = blockIdx.x;
    const int b   = ba >> 8;
    const int tid = threadIdx.x;
    __shared__ __attribute__((aligned(16))) bf sVij[64*128];   // 16 KB
    __shared__ float sVa[384];
    __shared__ float sC[64*4];
    __shared__ int   sJ[64];
    #pragma unroll
    for (int i = 0; i < 4; i++){
        int e8 = tid + i*256;
        *(bfrag8*)&sVij[e8*8] = *(const bfrag8*)&g_vij[(size_t)ba*8192 + e8*8];
    }
    for (int e = tid; e < 384; e += 256) sVa[e] = g_vik[ba*384 + e];
    if (tid < 64){
        int p = ba*64 + tid;
        sJ[tid] = (b*A + (nbrs[p] & (A-1)))*384;
        sC[tid*4+0] = cos_ij[p*3+0];
        sC[tid*4+1] = cos_ij[p*3+1];
        sC[tid*4+2] = cos_ij[p*3+2];
    }
    __syncthreads();
    float* const oBase = outV + (size_t)ba*24576;
    #pragma unroll 4
    for (int it = 0; it < 24; it++){
        int idx = (it*256 + tid)*4;            // 4 consecutive output floats
        int pl  = idx / 384;                   // pair-local (magic-mul)
        int e0  = idx - pl*384;
        ffrag4 va = *(const ffrag4*)&sVa[e0];
        ffrag4 vj = *(const ffrag4*)(g_vik + sJ[pl] + e0);
        ffrag4 o;
        #pragma unroll
        for (int j2 = 0; j2 < 4; j2++){
            int e = e0 + j2;
            int c = e / 3;
            int d = e - c*3;
            float vv = (float)sVij[pl*128 + c];
            o[j2] = fmaf(vv, sC[pl*4+d], va[j2] + vj[j2]);
        }
        __builtin_nontemporal_store(o, (ffrag4*)(oBase + idx));
    }
}

extern "C" void kernel_launch(void* const* d_in, const int* in_sizes, int n_in,
                              void* d_out, int out_size, void* d_ws, size_t ws_size,
                              hipStream_t stream){
    const float* xi      = (const float*)d_in[0];
    const float* r_ij    = (const float*)d_in[1];
    const float* cos_ij  = (const float*)d_in[2];
    const float* f_ij    = (const float*)d_in[3];
    const float* nmask   = (const float*)d_in[4];
    const float* fW1     = (const float*)d_in[5];
    const float* fb1     = (const float*)d_in[6];
    const float* fW2     = (const float*)d_in[7];
    const float* fb2     = (const float*)d_in[8];
    const float* in2f_W  = (const float*)d_in[9];
    const float* f2W     = (const float*)d_in[10];
    const float* f2b     = (const float*)d_in[11];
    const float* aW1     = (const float*)d_in[12];
    const float* ab1     = (const float*)d_in[13];
    const float* aW2     = (const float*)d_in[14];
    const float* ab2     = (const float*)d_in[15];
    const float* pW1     = (const float*)d_in[16];
    const float* pb1     = (const float*)d_in[17];
    const float* pW2     = (const float*)d_in[18];
    const float* pb2     = (const float*)d_in[19];
    const float* eW1     = (const float*)d_in[20];
    const float* eb1     = (const float*)d_in[21];
    const float* eW2     = (const float*)d_in[22];
    const float* eb2     = (const float*)d_in[23];
    const int*  nbrs     = (const int*)d_in[24];

    float* out_vi = (float*)d_out;             // [B,A,NCB] fp32
    float* outV   = (float*)d_out + BA*NCB;    // [B,A,N,NCB,3] fp32

    k_wt<<<56, 256, 0, stream>>>(fW1, fW2, f2W, pW1, pW2, eW1, eW2);
    k_yi<<<BA, NF, 0, stream>>>(xi, in2f_W);

    k_main<<<BA, 256, 0, stream>>>(r_ij, cos_ij, f_ij, nmask, nbrs,
                                   fb1, fb2, f2b,
                                   aW1, ab1, aW2, ab2,
                                   pb1, pb2, eb1, eb2,
                                   out_vi);

    k_V<<<BA, 256, 0, stream>>>(cos_ij, nbrs, outV);
}